// Round 2
// baseline (273.309 us; speedup 1.0000x reference)
//
#include <hip/hip_runtime.h>

#define EPS 1e-4f

constexpr int B = 2048;
constexpr int D = 3706;
constexpr unsigned BD = (unsigned)B * (unsigned)D;   // 7,589,888 elements
constexpr unsigned K4 = BD * 6u / 4u;                // 11,384,832 dist float4s
constexpr unsigned V4 = BD / 4u;                     //  1,896,448 val  float4s
constexpr unsigned NT = K4 + V4;                     // 13,281,280 = 51880*256
constexpr int BLOCK = 256;

// Boundaries in the reference's exact fp32 order: step = relu(L)+EPS first,
// then sequential cumsum adds (not reassociated). Bit-exact vs numpy ref.
__device__ __forceinline__ void bucketize(const float a, const float mb, const float4 L,
                                          int& cnt, float& ok) {
    const float s0 = fmaxf(L.x, 0.0f) + EPS;
    const float s1 = fmaxf(L.y, 0.0f) + EPS;
    const float s2 = fmaxf(L.z, 0.0f) + EPS;
    const float s3 = fmaxf(L.w, 0.0f) + EPS;
    const float b0 = mb;
    const float b1 = b0 + s0;
    const float b2 = b1 + s1;
    const float b3 = b2 + s2;
    const float b4 = b3 + s3;
    // strictly increasing boundaries -> {k : a > b_k} is a prefix
    cnt = (int)(a > b0) + (int)(a > b1) + (int)(a > b2)
        + (int)(a > b3) + (int)(a > b4);
    // heaviside(0)=0: equality with any boundary zeroes everything
    const bool eq = (a == b0) | (a == b1) | (a == b2) | (a == b3) | (a == b4);
    ok = eq ? 0.0f : 1.0f;
}

// One thread = one output float4 (perfectly coalesced stores; compute is
// recomputed per output slot — VALU was ~5% busy, recompute is free).
__global__ __launch_bounds__(BLOCK) void disc_kernel(
        const float* __restrict__ fake,
        const float* __restrict__ minb,
        const float* __restrict__ lens,
        float* __restrict__ out) {
    const unsigned id = blockIdx.x * BLOCK + threadIdx.x;   // < NT always (exact grid)

    if (id < K4) {
        // ---- dist float4 m: global slots g = 4m .. 4m+3; element = g/6 ----
        const unsigned m  = id;
        const unsigned e0 = (4u * m) / 6u;        // element of first slot
        const unsigned e1 = (4u * m + 3u) / 6u;   // element of last slot (e0 or e0+1)

        const unsigned d0 = e0 % (unsigned)D;
        int c0; float k0;
        bucketize(fake[e0], minb[d0],
                  reinterpret_cast<const float4*>(lens)[d0], c0, k0);

        const unsigned d1 = e1 % (unsigned)D;
        int c1; float k1;
        bucketize(fake[e1], minb[d1],
                  reinterpret_cast<const float4*>(lens)[d1], c1, k1);

        float4 f;
        float* fp = &f.x;
        const unsigned base = 4u * m;
#pragma unroll
        for (int j = 0; j < 4; ++j) {
            const unsigned g    = base + (unsigned)j;
            const unsigned e    = g / 6u;
            const unsigned slot = g - 6u * e;
            const int   cc = (e == e0) ? c0 : c1;
            const float kk = (e == e0) ? k0 : k1;
            fp[j] = ((int)slot == cc) ? kk : 0.0f;
        }
        reinterpret_cast<float4*>(out)[m] = f;
    } else {
        // ---- val float4 v: elements 4v .. 4v+3 ----
        const unsigned v = id - K4;
        const unsigned e = 4u * v;
        const float4 a4 = reinterpret_cast<const float4*>(fake)[v];
        const float* ap = &a4.x;
        float4 f;
        float* fp = &f.x;
#pragma unroll
        for (int j = 0; j < 4; ++j) {
            const unsigned ej = e + (unsigned)j;
            const unsigned dj = ej % (unsigned)D;
            int c; float k;
            bucketize(ap[j], minb[dj],
                      reinterpret_cast<const float4*>(lens)[dj], c, k);
            fp[j] = k * (float)c;   // eq ? 0 : cnt  (k in {0,1})
        }
        reinterpret_cast<float4*>(out + (size_t)BD * 6u)[v] = f;
    }
}

extern "C" void kernel_launch(void* const* d_in, const int* in_sizes, int n_in,
                              void* d_out, int out_size, void* d_ws, size_t ws_size,
                              hipStream_t stream) {
    const float* fake = (const float*)d_in[0];   // [B, D]
    const float* minb = (const float*)d_in[1];   // [D]
    const float* lens = (const float*)d_in[2];   // [D, 4]
    float* out = (float*)d_out;                  // dist [B,D,6] then val [B,D]

    const unsigned grid = NT / (unsigned)BLOCK;  // 51,880 exact, no tail
    disc_kernel<<<grid, BLOCK, 0, stream>>>(fake, minb, lens, out);
}

// Round 4
// 265.858 us; speedup vs baseline: 1.0280x; 1.0280x over previous
//
#include <hip/hip_runtime.h>

#define EPS 1e-4f

constexpr int B = 2048;
constexpr int D = 3706;
constexpr unsigned BD = (unsigned)B * (unsigned)D;   // 7,589,888 elements
constexpr unsigned K4 = BD * 6u / 4u;                // 11,384,832 dist float4s
constexpr unsigned V4 = BD / 4u;                     //  1,896,448 val  float4s
constexpr unsigned NT = K4 + V4;                     // 13,281,280 = 51880*256
constexpr int BLOCK = 256;

// native vector type (HIP's float4 is a class — nontemporal builtin rejects it)
typedef float f32x4 __attribute__((ext_vector_type(4)));

// Boundaries in the reference's exact fp32 order: step = relu(L)+EPS first,
// then sequential cumsum adds (not reassociated). Bit-exact vs numpy ref.
__device__ __forceinline__ void bucketize(const float a, const float mb, const f32x4 L,
                                          int& cnt, float& ok) {
    const float s0 = fmaxf(L.x, 0.0f) + EPS;
    const float s1 = fmaxf(L.y, 0.0f) + EPS;
    const float s2 = fmaxf(L.z, 0.0f) + EPS;
    const float s3 = fmaxf(L.w, 0.0f) + EPS;
    const float b0 = mb;
    const float b1 = b0 + s0;
    const float b2 = b1 + s1;
    const float b3 = b2 + s2;
    const float b4 = b3 + s3;
    // strictly increasing boundaries -> {k : a > b_k} is a prefix
    cnt = (int)(a > b0) + (int)(a > b1) + (int)(a > b2)
        + (int)(a > b3) + (int)(a > b4);
    // heaviside(0)=0: equality with any boundary zeroes everything
    const bool eq = (a == b0) | (a == b1) | (a == b2) | (a == b3) | (a == b4);
    ok = eq ? 0.0f : 1.0f;
}

// One thread = one output float4, stored NONTEMPORAL (output is write-once,
// never re-read; keep it out of L2 so the 30 MB `fake` working set stays
// resident for the dist path's re-reads).
__global__ __launch_bounds__(BLOCK) void disc_kernel(
        const float* __restrict__ fake,
        const float* __restrict__ minb,
        const float* __restrict__ lens,
        float* __restrict__ out) {
    const unsigned id = blockIdx.x * BLOCK + threadIdx.x;   // < NT always (exact grid)

    if (id < K4) {
        // ---- dist float4 m: global slots g = 4m .. 4m+3; element = g/6 ----
        const unsigned m  = id;
        const unsigned e0 = (4u * m) / 6u;        // element of first slot
        const unsigned e1 = (4u * m + 3u) / 6u;   // element of last slot (e0 or e0+1)

        const unsigned d0 = e0 % (unsigned)D;
        int c0; float k0;
        bucketize(fake[e0], minb[d0],
                  reinterpret_cast<const f32x4*>(lens)[d0], c0, k0);

        const unsigned d1 = e1 % (unsigned)D;
        int c1; float k1;
        bucketize(fake[e1], minb[d1],
                  reinterpret_cast<const f32x4*>(lens)[d1], c1, k1);

        f32x4 f;
        const unsigned base = 4u * m;
#pragma unroll
        for (int j = 0; j < 4; ++j) {
            const unsigned g    = base + (unsigned)j;
            const unsigned e    = g / 6u;
            const unsigned slot = g - 6u * e;
            const int   cc = (e == e0) ? c0 : c1;
            const float kk = (e == e0) ? k0 : k1;
            f[j] = ((int)slot == cc) ? kk : 0.0f;
        }
        __builtin_nontemporal_store(f, reinterpret_cast<f32x4*>(out) + m);
    } else {
        // ---- val float4 v: elements 4v .. 4v+3 ----
        const unsigned v = id - K4;
        const unsigned e = 4u * v;
        const f32x4 a4 = reinterpret_cast<const f32x4*>(fake)[v];
        f32x4 f;
#pragma unroll
        for (int j = 0; j < 4; ++j) {
            const unsigned ej = e + (unsigned)j;
            const unsigned dj = ej % (unsigned)D;
            int c; float k;
            bucketize(a4[j], minb[dj],
                      reinterpret_cast<const f32x4*>(lens)[dj], c, k);
            f[j] = k * (float)c;   // eq ? 0 : cnt  (k in {0,1})
        }
        __builtin_nontemporal_store(
            f, reinterpret_cast<f32x4*>(out + (size_t)BD * 6u) + v);
    }
}

extern "C" void kernel_launch(void* const* d_in, const int* in_sizes, int n_in,
                              void* d_out, int out_size, void* d_ws, size_t ws_size,
                              hipStream_t stream) {
    const float* fake = (const float*)d_in[0];   // [B, D]
    const float* minb = (const float*)d_in[1];   // [D]
    const float* lens = (const float*)d_in[2];   // [D, 4]
    float* out = (float*)d_out;                  // dist [B,D,6] then val [B,D]

    const unsigned grid = NT / (unsigned)BLOCK;  // 51,880 exact, no tail
    disc_kernel<<<grid, BLOCK, 0, stream>>>(fake, minb, lens, out);
}